// Round 1
// baseline (429.443 us; speedup 1.0000x reference)
//
#include <hip/hip_runtime.h>

// ActivatedAttention: y = GroupNorm( relu(rope(Q)) @ [relu(rope(K))^T @ relu(V)] ), transposed store.
// B=4, T=2048, D=1024, qkv GEMM: (8192x1024)@(1024x3072).
// Workspace requirement: ~189 MB (layout documented in kernel_launch).

typedef unsigned short u16;
typedef __attribute__((ext_vector_type(8))) unsigned short u16x8;
typedef __attribute__((ext_vector_type(4))) float fx4;
typedef __attribute__((ext_vector_type(8))) __bf16 bfx8;

#define LDS_PITCH 40  // 32 + 8 pad (ushorts) -> 80B row pitch, 16B aligned, conflict-light

__device__ __forceinline__ u16 f2bh(float v) {  // f32 -> bf16 RNE
  unsigned u = __float_as_uint(v);
  return (u16)((u + 0x7FFFu + ((u >> 16) & 1u)) >> 16);
}
__device__ __forceinline__ float bh2f(u16 h) {
  return __uint_as_float((unsigned)h << 16);
}
__device__ __forceinline__ void split2(float v, u16& hi, u16& lo) {
  hi = f2bh(v);
  lo = f2bh(v - bh2f(hi));  // exact residual (Sterbenz), lo captures next 8 mantissa bits
}

__device__ __forceinline__ fx4 mfma16(bfx8 a, bfx8 b, fx4 c) {
  return __builtin_amdgcn_mfma_f32_16x16x32_bf16(a, b, c, 0, 0, 0);
}

// Copy 128 rows x 32 bf16 from global (row-major, k-contiguous) into LDS [128][LDS_PITCH]
__device__ __forceinline__ void stage(const u16* __restrict__ src, size_t rowBase, int stride,
                                      int k0, u16* lds, int tid) {
#pragma unroll
  for (int i = 0; i < 2; ++i) {
    int flat = tid + i * 256;       // 0..511 = 128 rows * 4 segs
    int r = flat >> 2;
    int seg = (flat & 3) * 8;
    u16x8 v = *reinterpret_cast<const u16x8*>(src + (rowBase + (size_t)r) * (size_t)stride + k0 + seg);
    *reinterpret_cast<u16x8*>(lds + r * LDS_PITCH + seg) = v;
  }
}

__device__ __forceinline__ bfx8 ldfrag(const u16* lds, int row, int lk) {
  u16x8 v = *reinterpret_cast<const u16x8*>(lds + row * LDS_PITCH + lk * 8);
  return __builtin_bit_cast(bfx8, v);
}

// Generic 128x128 tile GEMM, split-precision bf16 (3 MFMA products), K multiple of 32.
// A: [M][K] row-major (hi/lo), B: stored transposed [N][K] row-major (hi/lo).
__device__ inline void gemm_tile(const u16* __restrict__ Ah_g, const u16* __restrict__ Al_g,
                                 size_t aBase, int aStride,
                                 const u16* __restrict__ Bh_g, const u16* __restrict__ Bl_g,
                                 size_t bBase, int bStride, int K,
                                 u16* sAh, u16* sAl, u16* sBh, u16* sBl,
                                 fx4 acc[4][4]) {
  int tid = threadIdx.x;
  int l = tid & 63, w = tid >> 6;
  int wm = (w >> 1) * 64, wn = (w & 1) * 64;
  int lr = l & 15, lk = l >> 4;
  for (int k0 = 0; k0 < K; k0 += 32) {
    __syncthreads();
    stage(Ah_g, aBase, aStride, k0, sAh, tid);
    stage(Al_g, aBase, aStride, k0, sAl, tid);
    stage(Bh_g, bBase, bStride, k0, sBh, tid);
    stage(Bl_g, bBase, bStride, k0, sBl, tid);
    __syncthreads();
    bfx8 ah[4], al[4], bh[4], bl[4];
#pragma unroll
    for (int i = 0; i < 4; ++i) {
      ah[i] = ldfrag(sAh, wm + i * 16 + lr, lk);
      al[i] = ldfrag(sAl, wm + i * 16 + lr, lk);
      bh[i] = ldfrag(sBh, wn + i * 16 + lr, lk);
      bl[i] = ldfrag(sBl, wn + i * 16 + lr, lk);
    }
#pragma unroll
    for (int mi = 0; mi < 4; ++mi)
#pragma unroll
      for (int ni = 0; ni < 4; ++ni) {
        acc[mi][ni] = mfma16(ah[mi], bh[ni], acc[mi][ni]);
        acc[mi][ni] = mfma16(ah[mi], bl[ni], acc[mi][ni]);
        acc[mi][ni] = mfma16(al[mi], bh[ni], acc[mi][ni]);
      }
  }
}

// ---- K0b: transpose + split W (1024x3072 f32) -> WT[3072][1024] hi/lo bf16
__global__ void k_transW(const float* __restrict__ W, u16* __restrict__ WTh, u16* __restrict__ WTl) {
  __shared__ float tile[32][33];
  int n0 = blockIdx.x * 32, k0 = blockIdx.y * 32;
  int tid = threadIdx.x;
  int c = tid & 31, r4 = tid >> 5;
#pragma unroll
  for (int it = 0; it < 4; ++it) {
    int r = r4 + it * 8;
    tile[r][c] = W[(size_t)(k0 + r) * 3072 + n0 + c];
  }
  __syncthreads();
#pragma unroll
  for (int it = 0; it < 4; ++it) {
    int r = r4 + it * 8;
    float v = tile[c][r];  // = W[k0+c][n0+r]
    u16 hi, lo;
    split2(v, hi, lo);
    size_t o = (size_t)(n0 + r) * 1024 + k0 + c;
    WTh[o] = hi;
    WTl[o] = lo;
  }
}

// ---- K0c: elementwise split x -> xh/xl
__global__ void k_splitX(const float* __restrict__ x, u16* __restrict__ xh, u16* __restrict__ xl, int n) {
  int i = blockIdx.x * 256 + threadIdx.x;
  if (i < n) {
    u16 h, l;
    split2(x[i], h, l);
    xh[i] = h;
    xl[i] = l;
  }
}

// ---- G1: qkv_half = x[row0..row0+4096) @ W + b  (f32 out, local rows)
__global__ __launch_bounds__(256) void k_gemm1(const u16* __restrict__ xh, const u16* __restrict__ xl,
                                               const u16* __restrict__ WTh, const u16* __restrict__ WTl,
                                               const float* __restrict__ b_in, float* __restrict__ qkv,
                                               int row0) {
  __shared__ u16 sAh[128 * LDS_PITCH], sAl[128 * LDS_PITCH], sBh[128 * LDS_PITCH], sBl[128 * LDS_PITCH];
  fx4 acc[4][4];
#pragma unroll
  for (int i = 0; i < 4; ++i)
#pragma unroll
    for (int j = 0; j < 4; ++j) acc[i][j] = fx4{0.f, 0.f, 0.f, 0.f};
  int m0 = blockIdx.x * 128, n0 = blockIdx.y * 128;
  gemm_tile(xh, xl, (size_t)(row0 + m0), 1024, WTh, WTl, (size_t)n0, 1024, 1024, sAh, sAl, sBh, sBl, acc);
  int tid = threadIdx.x, l = tid & 63, w = tid >> 6;
  int wm = (w >> 1) * 64, wn = (w & 1) * 64, lr = l & 15, lk = l >> 4;
#pragma unroll
  for (int mi = 0; mi < 4; ++mi)
#pragma unroll
    for (int ni = 0; ni < 4; ++ni)
#pragma unroll
      for (int r = 0; r < 4; ++r) {
        int m = m0 + wm + mi * 16 + lk * 4 + r;
        int n = n0 + wn + ni * 16 + lr;
        qkv[(size_t)m * 3072 + n] = acc[mi][ni][r] + b_in[n];
      }
}

// ---- K2q: rope+relu+split for Q (row-major out, global rows)
__global__ void k_rope_q(const float* __restrict__ qkv, u16* __restrict__ Qh, u16* __restrict__ Ql, int row0) {
  int idx = blockIdx.x * 256 + threadIdx.x;  // over 4096*512 pairs
  if (idx >= 4096 * 512) return;
  int r = idx >> 9, i = idx & 511;
  int t = (row0 + r) & 2047;
  const float* p = qkv + (size_t)r * 3072 + 2 * i;
  float x1 = p[0], x2 = p[1];
  float invf = powf(10000.f, -(float)i * (1.f / 512.f));
  float f = (float)t * invf, s, c;
  sincosf(f, &s, &c);
  float r1 = fmaxf(x1 * c - x2 * s, 0.f);
  float r2 = fmaxf(x1 * s + x2 * c, 0.f);
  u16 h, l;
  size_t o = (size_t)(row0 + r) * 1024 + 2 * i;
  split2(r1, h, l);
  Qh[o] = h;
  Ql[o] = l;
  split2(r2, h, l);
  Qh[o + 1] = h;
  Ql[o + 1] = l;
}

// ---- K2t: (rope+)relu+split+transpose for K (part=0) / V (part=1): out [B][D][T]
__global__ void k_ropeT(const float* __restrict__ qkv, u16* __restrict__ Th, u16* __restrict__ Tl,
                        int row0, int part) {
  __shared__ float tile[32][33];
  int t0 = blockIdx.x * 32;  // local row within half
  int d0 = blockIdx.y * 32;
  int tid = threadIdx.x;
  int cc = tid & 31, rr = tid >> 5;
  int colbase = (part == 0) ? 1024 : 2048;
#pragma unroll
  for (int it = 0; it < 4; ++it) {
    int r = rr + it * 8;
    tile[r][cc] = qkv[(size_t)(t0 + r) * 3072 + colbase + d0 + cc];
  }
  __syncthreads();
  int grow0 = row0 + t0;
  int b = grow0 >> 11;
  int tbase = grow0 & 2047;
  if (part == 0) {
#pragma unroll
    for (int pass = 0; pass < 2; ++pass) {
      int idx = tid + pass * 256;  // 512 items: (pair p 0..15, t 0..31)
      int tl = idx & 31, p = idx >> 5;
      float x1 = tile[tl][2 * p], x2 = tile[tl][2 * p + 1];
      int i = (d0 >> 1) + p;
      float invf = powf(10000.f, -(float)i * (1.f / 512.f));
      float f = (float)(tbase + tl) * invf, s, c;
      sincosf(f, &s, &c);
      float r1 = fmaxf(x1 * c - x2 * s, 0.f);
      float r2 = fmaxf(x1 * s + x2 * c, 0.f);
      u16 h, l;
      size_t o1 = ((size_t)(b * 1024 + d0 + 2 * p)) * 2048 + tbase + tl;
      split2(r1, h, l);
      Th[o1] = h;
      Tl[o1] = l;
      size_t o2 = o1 + 2048;
      split2(r2, h, l);
      Th[o2] = h;
      Tl[o2] = l;
    }
  } else {
#pragma unroll
    for (int pass = 0; pass < 4; ++pass) {
      int idx = tid + pass * 256;  // 1024 items: (dd 0..31, t 0..31)
      int tl = idx & 31, dd = idx >> 5;
      float v = fmaxf(tile[tl][dd], 0.f);
      u16 h, l;
      split2(v, h, l);
      size_t o = ((size_t)(b * 1024 + d0 + dd)) * 2048 + tbase + tl;
      Th[o] = h;
      Tl[o] = l;
    }
  }
}

// ---- G2: KtVT[b][n][m] = (K^T V)[m][n], split bf16 out
__global__ __launch_bounds__(256) void k_gemm2(const u16* __restrict__ Kth, const u16* __restrict__ Ktl,
                                               const u16* __restrict__ Vth, const u16* __restrict__ Vtl,
                                               u16* __restrict__ KtVTh, u16* __restrict__ KtVTl) {
  __shared__ u16 sAh[128 * LDS_PITCH], sAl[128 * LDS_PITCH], sBh[128 * LDS_PITCH], sBl[128 * LDS_PITCH];
  fx4 acc[4][4];
#pragma unroll
  for (int i = 0; i < 4; ++i)
#pragma unroll
    for (int j = 0; j < 4; ++j) acc[i][j] = fx4{0.f, 0.f, 0.f, 0.f};
  int b = blockIdx.z;
  int m0 = blockIdx.x * 128, n0 = blockIdx.y * 128;
  size_t bb = (size_t)b * 1024 * 2048;
  gemm_tile(Kth + bb, Ktl + bb, (size_t)m0, 2048, Vth + bb, Vtl + bb, (size_t)n0, 2048, 2048,
            sAh, sAl, sBh, sBl, acc);
  int tid = threadIdx.x, l = tid & 63, w = tid >> 6;
  int wm = (w >> 1) * 64, wn = (w & 1) * 64, lr = l & 15, lk = l >> 4;
#pragma unroll
  for (int mi = 0; mi < 4; ++mi)
#pragma unroll
    for (int ni = 0; ni < 4; ++ni)
#pragma unroll
      for (int r = 0; r < 4; ++r) {
        int m = m0 + wm + mi * 16 + lk * 4 + r;
        int n = n0 + wn + ni * 16 + lr;
        u16 h, lo2;
        split2(acc[mi][ni][r], h, lo2);
        size_t o = ((size_t)b << 20) + (size_t)n * 1024 + m;
        KtVTh[o] = h;
        KtVTl[o] = lo2;
      }
}

// ---- G3: y[b][t][n] = Q[b] @ KtV[b]  (f32 out)
__global__ __launch_bounds__(256) void k_gemm3(const u16* __restrict__ Qh, const u16* __restrict__ Ql,
                                               const u16* __restrict__ KtVTh, const u16* __restrict__ KtVTl,
                                               float* __restrict__ y) {
  __shared__ u16 sAh[128 * LDS_PITCH], sAl[128 * LDS_PITCH], sBh[128 * LDS_PITCH], sBl[128 * LDS_PITCH];
  fx4 acc[4][4];
#pragma unroll
  for (int i = 0; i < 4; ++i)
#pragma unroll
    for (int j = 0; j < 4; ++j) acc[i][j] = fx4{0.f, 0.f, 0.f, 0.f};
  int b = blockIdx.z;
  int m0 = blockIdx.x * 128, n0 = blockIdx.y * 128;
  gemm_tile(Qh, Ql, (size_t)(b * 2048 + m0), 1024, KtVTh + ((size_t)b << 20), KtVTl + ((size_t)b << 20),
            (size_t)n0, 1024, 1024, sAh, sAl, sBh, sBl, acc);
  int tid = threadIdx.x, l = tid & 63, w = tid >> 6;
  int wm = (w >> 1) * 64, wn = (w & 1) * 64, lr = l & 15, lk = l >> 4;
#pragma unroll
  for (int mi = 0; mi < 4; ++mi)
#pragma unroll
    for (int ni = 0; ni < 4; ++ni)
#pragma unroll
      for (int r = 0; r < 4; ++r) {
        int m = m0 + wm + mi * 16 + lk * 4 + r;
        int n = n0 + wn + ni * 16 + lr;
        y[((size_t)b * 2048 + m) * 1024 + n] = acc[mi][ni][r];
      }
}

// ---- K5: GroupNorm (groups of 32 channels, two-pass) + transposed store out[b][d][t]
__global__ void k_gnorm(const float* __restrict__ y, const float* __restrict__ w,
                        const float* __restrict__ bias, float* __restrict__ out) {
  __shared__ float tile[32][33];
  __shared__ float meanS[32], rstdS[32];
  int t0 = blockIdx.x * 32;
  int g = blockIdx.y;
  int b = blockIdx.z;
  int tid = threadIdx.x;
  int cc = tid & 31, rr = tid >> 5;
#pragma unroll
  for (int it = 0; it < 4; ++it) {
    int r = rr + it * 8;
    tile[r][cc] = y[((size_t)(b * 2048 + t0 + r)) * 1024 + g * 32 + cc];
  }
  __syncthreads();
  if (tid < 32) {
    float s = 0.f;
#pragma unroll
    for (int j = 0; j < 32; ++j) s += tile[tid][j];
    float m = s * (1.f / 32.f);
    float v = 0.f;
#pragma unroll
    for (int j = 0; j < 32; ++j) {
      float d = tile[tid][j] - m;
      v += d * d;
    }
    meanS[tid] = m;
    rstdS[tid] = rsqrtf(v * (1.f / 32.f) + 1e-5f);
  }
  __syncthreads();
#pragma unroll
  for (int it = 0; it < 4; ++it) {
    int idx = tid + it * 256;
    int tl = idx & 31, dd = idx >> 5;
    float val = (tile[tl][dd] - meanS[tl]) * rstdS[tl];
    val = val * w[g * 32 + dd] + bias[g * 32 + dd];
    out[((size_t)(b * 1024 + g * 32 + dd)) * 2048 + t0 + tl] = val;
  }
}

extern "C" void kernel_launch(void* const* d_in, const int* in_sizes, int n_in,
                              void* d_out, int out_size, void* d_ws, size_t ws_size,
                              hipStream_t stream) {
  const float* x = (const float*)d_in[0];
  const float* W = (const float*)d_in[1];
  const float* b_in = (const float*)d_in[2];
  const float* gnw = (const float*)d_in[3];
  const float* gnb = (const float*)d_in[4];
  float* out = (float*)d_out;
  char* ws = (char*)d_ws;

  // Workspace layout (bytes):
  //  R1 (dead after last k_gemm1; KtVT overlaid here after):
  //   [0,        6291456)   WTh
  //   [6291456,  12582912)  WTl
  //   [12582912, 29360128)  xh
  //   [29360128, 46137344)  xl
  //   overlay: KtVTh @ 0 (8388608), KtVTl @ 8388608 (8388608)
  //  [46137344, 96468992)   qkv_half f32 (4096x3072); overlay: y f32 (8192x1024, 33554432)
  //  [96468992, 197132288)  Qh,Ql,Kth,Ktl,Vth,Vtl (6 x 16777216)
  u16* WTh = (u16*)(ws + 0);
  u16* WTl = (u16*)(ws + 6291456);
  u16* xh = (u16*)(ws + 12582912);
  u16* xl = (u16*)(ws + 29360128);
  u16* KtVTh = (u16*)(ws + 0);
  u16* KtVTl = (u16*)(ws + 8388608);
  float* qkv = (float*)(ws + 46137344);
  float* y = (float*)(ws + 46137344);
  u16* Qh = (u16*)(ws + 96468992);
  u16* Ql = (u16*)(ws + 96468992 + 16777216);
  u16* Kth = (u16*)(ws + 96468992 + 2 * 16777216);
  u16* Ktl = (u16*)(ws + 96468992 + 3 * 16777216);
  u16* Vth = (u16*)(ws + 96468992 + 4 * 16777216);
  u16* Vtl = (u16*)(ws + 96468992 + 5 * 16777216);

  k_transW<<<dim3(96, 32), 256, 0, stream>>>(W, WTh, WTl);
  k_splitX<<<32768, 256, 0, stream>>>(x, xh, xl, 8388608);

  for (int h = 0; h < 2; ++h) {
    int row0 = h * 4096;
    k_gemm1<<<dim3(32, 24), 256, 0, stream>>>(xh, xl, WTh, WTl, b_in, qkv, row0);
    k_rope_q<<<8192, 256, 0, stream>>>(qkv, Qh, Ql, row0);
    k_ropeT<<<dim3(128, 32), 256, 0, stream>>>(qkv, Kth, Ktl, row0, 0);
    k_ropeT<<<dim3(128, 32), 256, 0, stream>>>(qkv, Vth, Vtl, row0, 1);
  }

  k_gemm2<<<dim3(8, 8, 4), 256, 0, stream>>>(Kth, Ktl, Vth, Vtl, KtVTh, KtVTl);
  k_gemm3<<<dim3(16, 8, 4), 256, 0, stream>>>(Qh, Ql, KtVTh, KtVTl, y);
  k_gnorm<<<dim3(64, 32, 4), 256, 0, stream>>>(y, gnw, gnb, out);
}

// Round 2
// 326.981 us; speedup vs baseline: 1.3134x; 1.3134x over previous
//
#include <hip/hip_runtime.h>

// ActivatedAttention: y = GroupNorm( relu(rope(Q)) @ [relu(rope(K))^T @ relu(V)] ), transposed store.
// B=4, T=2048, D=1024, qkv GEMM: (8192x1024)@(1024x3072).
// Precision plan: gemm1 = split-bf16 (3 MFMA products). gemm2/gemm3 operate on
// non-negative (post-ReLU) data -> coherent accumulation -> hi-only bf16 (1 product).

typedef unsigned short u16;
typedef __attribute__((ext_vector_type(8))) unsigned short u16x8;
typedef __attribute__((ext_vector_type(4))) float fx4;
typedef __attribute__((ext_vector_type(8))) __bf16 bfx8;

#define LDS_PITCH 40  // 32 + 8 pad (ushorts) -> 80B row pitch, 16B aligned, conflict-light

__device__ __forceinline__ u16 f2bh(float v) {  // f32 -> bf16 RNE
  unsigned u = __float_as_uint(v);
  return (u16)((u + 0x7FFFu + ((u >> 16) & 1u)) >> 16);
}
__device__ __forceinline__ float bh2f(u16 h) {
  return __uint_as_float((unsigned)h << 16);
}
__device__ __forceinline__ void split2(float v, u16& hi, u16& lo) {
  hi = f2bh(v);
  lo = f2bh(v - bh2f(hi));  // residual captures next 8 mantissa bits
}

__device__ __forceinline__ fx4 mfma16(bfx8 a, bfx8 b, fx4 c) {
  return __builtin_amdgcn_mfma_f32_16x16x32_bf16(a, b, c, 0, 0, 0);
}

// Copy 128 rows x 32 bf16 from global (row-major, k-contiguous) into LDS [128][LDS_PITCH]
__device__ __forceinline__ void stage(const u16* __restrict__ src, size_t rowBase, int stride,
                                      int k0, u16* lds, int tid) {
#pragma unroll
  for (int i = 0; i < 2; ++i) {
    int flat = tid + i * 256;       // 0..511 = 128 rows * 4 segs
    int r = flat >> 2;
    int seg = (flat & 3) * 8;
    u16x8 v = *reinterpret_cast<const u16x8*>(src + (rowBase + (size_t)r) * (size_t)stride + k0 + seg);
    *reinterpret_cast<u16x8*>(lds + r * LDS_PITCH + seg) = v;
  }
}

__device__ __forceinline__ bfx8 ldfrag(const u16* lds, int row, int lk) {
  u16x8 v = *reinterpret_cast<const u16x8*>(lds + row * LDS_PITCH + lk * 8);
  return __builtin_bit_cast(bfx8, v);
}

// 128x128 tile GEMM, split-precision bf16 (3 MFMA products), K multiple of 32.
// A: [M][K] row-major (hi/lo), B: stored transposed [N][K] row-major (hi/lo).
__device__ inline void gemm_tile(const u16* __restrict__ Ah_g, const u16* __restrict__ Al_g,
                                 size_t aBase, int aStride,
                                 const u16* __restrict__ Bh_g, const u16* __restrict__ Bl_g,
                                 size_t bBase, int bStride, int K,
                                 u16* sAh, u16* sAl, u16* sBh, u16* sBl,
                                 fx4 acc[4][4]) {
  int tid = threadIdx.x;
  int l = tid & 63, w = tid >> 6;
  int wm = (w >> 1) * 64, wn = (w & 1) * 64;
  int lr = l & 15, lk = l >> 4;
  for (int k0 = 0; k0 < K; k0 += 32) {
    __syncthreads();
    stage(Ah_g, aBase, aStride, k0, sAh, tid);
    stage(Al_g, aBase, aStride, k0, sAl, tid);
    stage(Bh_g, bBase, bStride, k0, sBh, tid);
    stage(Bl_g, bBase, bStride, k0, sBl, tid);
    __syncthreads();
    bfx8 ah[4], al[4], bh[4], bl[4];
#pragma unroll
    for (int i = 0; i < 4; ++i) {
      ah[i] = ldfrag(sAh, wm + i * 16 + lr, lk);
      al[i] = ldfrag(sAl, wm + i * 16 + lr, lk);
      bh[i] = ldfrag(sBh, wn + i * 16 + lr, lk);
      bl[i] = ldfrag(sBl, wn + i * 16 + lr, lk);
    }
#pragma unroll
    for (int mi = 0; mi < 4; ++mi)
#pragma unroll
      for (int ni = 0; ni < 4; ++ni) {
        acc[mi][ni] = mfma16(ah[mi], bh[ni], acc[mi][ni]);
        acc[mi][ni] = mfma16(ah[mi], bl[ni], acc[mi][ni]);
        acc[mi][ni] = mfma16(al[mi], bh[ni], acc[mi][ni]);
      }
  }
}

// 128x128 tile GEMM, hi-only bf16 (1 MFMA product). Valid when accumulation is
// coherent (non-negative operands): rounding errors cancel relative to the sum.
__device__ inline void gemm_tile_hi(const u16* __restrict__ A_g, size_t aBase, int aStride,
                                    const u16* __restrict__ B_g, size_t bBase, int bStride, int K,
                                    u16* sA, u16* sB, fx4 acc[4][4]) {
  int tid = threadIdx.x;
  int l = tid & 63, w = tid >> 6;
  int wm = (w >> 1) * 64, wn = (w & 1) * 64;
  int lr = l & 15, lk = l >> 4;
  for (int k0 = 0; k0 < K; k0 += 32) {
    __syncthreads();
    stage(A_g, aBase, aStride, k0, sA, tid);
    stage(B_g, bBase, bStride, k0, sB, tid);
    __syncthreads();
    bfx8 a[4], b[4];
#pragma unroll
    for (int i = 0; i < 4; ++i) {
      a[i] = ldfrag(sA, wm + i * 16 + lr, lk);
      b[i] = ldfrag(sB, wn + i * 16 + lr, lk);
    }
#pragma unroll
    for (int mi = 0; mi < 4; ++mi)
#pragma unroll
      for (int ni = 0; ni < 4; ++ni)
        acc[mi][ni] = mfma16(a[mi], b[ni], acc[mi][ni]);
  }
}

// ---- K0b: transpose + split W (1024x3072 f32) -> WT[3072][1024] hi/lo bf16
__global__ void k_transW(const float* __restrict__ W, u16* __restrict__ WTh, u16* __restrict__ WTl) {
  __shared__ float tile[32][33];
  int n0 = blockIdx.x * 32, k0 = blockIdx.y * 32;
  int tid = threadIdx.x;
  int c = tid & 31, r4 = tid >> 5;
#pragma unroll
  for (int it = 0; it < 4; ++it) {
    int r = r4 + it * 8;
    tile[r][c] = W[(size_t)(k0 + r) * 3072 + n0 + c];
  }
  __syncthreads();
#pragma unroll
  for (int it = 0; it < 4; ++it) {
    int r = r4 + it * 8;
    float v = tile[c][r];  // = W[k0+c][n0+r]
    u16 hi, lo;
    split2(v, hi, lo);
    size_t o = (size_t)(n0 + r) * 1024 + k0 + c;
    WTh[o] = hi;
    WTl[o] = lo;
  }
}

// ---- K0c: elementwise split x -> xh/xl
__global__ void k_splitX(const float* __restrict__ x, u16* __restrict__ xh, u16* __restrict__ xl, int n) {
  int i = blockIdx.x * 256 + threadIdx.x;
  if (i < n) {
    u16 h, l;
    split2(x[i], h, l);
    xh[i] = h;
    xl[i] = l;
  }
}

// ---- G1: qkv_half = x[row0..row0+4096) @ W + b  (f32 out, local rows)
__global__ __launch_bounds__(256) void k_gemm1(const u16* __restrict__ xh, const u16* __restrict__ xl,
                                               const u16* __restrict__ WTh, const u16* __restrict__ WTl,
                                               const float* __restrict__ b_in, float* __restrict__ qkv,
                                               int row0) {
  __shared__ u16 sAh[128 * LDS_PITCH], sAl[128 * LDS_PITCH], sBh[128 * LDS_PITCH], sBl[128 * LDS_PITCH];
  fx4 acc[4][4];
#pragma unroll
  for (int i = 0; i < 4; ++i)
#pragma unroll
    for (int j = 0; j < 4; ++j) acc[i][j] = fx4{0.f, 0.f, 0.f, 0.f};
  int m0 = blockIdx.x * 128, n0 = blockIdx.y * 128;
  gemm_tile(xh, xl, (size_t)(row0 + m0), 1024, WTh, WTl, (size_t)n0, 1024, 1024, sAh, sAl, sBh, sBl, acc);
  int tid = threadIdx.x, l = tid & 63, w = tid >> 6;
  int wm = (w >> 1) * 64, wn = (w & 1) * 64, lr = l & 15, lk = l >> 4;
#pragma unroll
  for (int mi = 0; mi < 4; ++mi)
#pragma unroll
    for (int ni = 0; ni < 4; ++ni)
#pragma unroll
      for (int r = 0; r < 4; ++r) {
        int m = m0 + wm + mi * 16 + lk * 4 + r;
        int n = n0 + wn + ni * 16 + lr;
        qkv[(size_t)m * 3072 + n] = acc[mi][ni][r] + b_in[n];
      }
}

// ---- K2q: rope+relu for Q (hi-only bf16 out, row-major, global rows)
__global__ void k_rope_q(const float* __restrict__ qkv, u16* __restrict__ Qh, int row0) {
  int idx = blockIdx.x * 256 + threadIdx.x;  // over 4096*512 pairs
  if (idx >= 4096 * 512) return;
  int r = idx >> 9, i = idx & 511;
  int t = (row0 + r) & 2047;
  const float* p = qkv + (size_t)r * 3072 + 2 * i;
  float x1 = p[0], x2 = p[1];
  float invf = exp2f(-(float)i * (13.287712379549449f / 512.f));  // 10000^(-i/512)
  float f = (float)t * invf, s, c;
  sincosf(f, &s, &c);
  float r1 = fmaxf(x1 * c - x2 * s, 0.f);
  float r2 = fmaxf(x1 * s + x2 * c, 0.f);
  size_t o = (size_t)(row0 + r) * 1024 + 2 * i;
  Qh[o] = f2bh(r1);
  Qh[o + 1] = f2bh(r2);
}

// ---- K2t: (rope+)relu+transpose for K (part=0) / V (part=1): hi-only out [B][D][T]
__global__ void k_ropeT(const float* __restrict__ qkv, u16* __restrict__ Th, int row0, int part) {
  __shared__ float tile[32][33];
  int t0 = blockIdx.x * 32;  // local row within half
  int d0 = blockIdx.y * 32;
  int tid = threadIdx.x;
  int cc = tid & 31, rr = tid >> 5;
  int colbase = (part == 0) ? 1024 : 2048;
#pragma unroll
  for (int it = 0; it < 4; ++it) {
    int r = rr + it * 8;
    tile[r][cc] = qkv[(size_t)(t0 + r) * 3072 + colbase + d0 + cc];
  }
  __syncthreads();
  int grow0 = row0 + t0;
  int b = grow0 >> 11;
  int tbase = grow0 & 2047;
  if (part == 0) {
#pragma unroll
    for (int pass = 0; pass < 2; ++pass) {
      int idx = tid + pass * 256;  // 512 items: (pair p 0..15, t 0..31)
      int tl = idx & 31, p = idx >> 5;
      float x1 = tile[tl][2 * p], x2 = tile[tl][2 * p + 1];
      int i = (d0 >> 1) + p;
      float invf = exp2f(-(float)i * (13.287712379549449f / 512.f));
      float f = (float)(tbase + tl) * invf, s, c;
      sincosf(f, &s, &c);
      float r1 = fmaxf(x1 * c - x2 * s, 0.f);
      float r2 = fmaxf(x1 * s + x2 * c, 0.f);
      size_t o1 = ((size_t)(b * 1024 + d0 + 2 * p)) * 2048 + tbase + tl;
      Th[o1] = f2bh(r1);
      Th[o1 + 2048] = f2bh(r2);
    }
  } else {
#pragma unroll
    for (int pass = 0; pass < 4; ++pass) {
      int idx = tid + pass * 256;  // 1024 items: (dd 0..31, t 0..31)
      int tl = idx & 31, dd = idx >> 5;
      float v = fmaxf(tile[tl][dd], 0.f);
      size_t o = ((size_t)(b * 1024 + d0 + dd)) * 2048 + tbase + tl;
      Th[o] = f2bh(v);
    }
  }
}

// ---- G2: KtVT[b][n][m] = (K^T V)[m][n], hi-only bf16 out
__global__ __launch_bounds__(256) void k_gemm2(const u16* __restrict__ Kth, const u16* __restrict__ Vth,
                                               u16* __restrict__ KtVTh) {
  __shared__ u16 sA[128 * LDS_PITCH], sB[128 * LDS_PITCH];
  fx4 acc[4][4];
#pragma unroll
  for (int i = 0; i < 4; ++i)
#pragma unroll
    for (int j = 0; j < 4; ++j) acc[i][j] = fx4{0.f, 0.f, 0.f, 0.f};
  int b = blockIdx.z;
  int m0 = blockIdx.x * 128, n0 = blockIdx.y * 128;
  size_t bb = (size_t)b * 1024 * 2048;
  gemm_tile_hi(Kth + bb, (size_t)m0, 2048, Vth + bb, (size_t)n0, 2048, 2048, sA, sB, acc);
  int tid = threadIdx.x, l = tid & 63, w = tid >> 6;
  int wm = (w >> 1) * 64, wn = (w & 1) * 64, lr = l & 15, lk = l >> 4;
#pragma unroll
  for (int mi = 0; mi < 4; ++mi)
#pragma unroll
    for (int ni = 0; ni < 4; ++ni)
#pragma unroll
      for (int r = 0; r < 4; ++r) {
        int m = m0 + wm + mi * 16 + lk * 4 + r;
        int n = n0 + wn + ni * 16 + lr;
        size_t o = ((size_t)b << 20) + (size_t)n * 1024 + m;
        KtVTh[o] = f2bh(acc[mi][ni][r]);
      }
}

// ---- G3: y[b][t][n] = Q[b] @ KtV[b]  (f32 out), hi-only inputs
__global__ __launch_bounds__(256) void k_gemm3(const u16* __restrict__ Qh, const u16* __restrict__ KtVTh,
                                               float* __restrict__ y) {
  __shared__ u16 sA[128 * LDS_PITCH], sB[128 * LDS_PITCH];
  fx4 acc[4][4];
#pragma unroll
  for (int i = 0; i < 4; ++i)
#pragma unroll
    for (int j = 0; j < 4; ++j) acc[i][j] = fx4{0.f, 0.f, 0.f, 0.f};
  int b = blockIdx.z;
  int m0 = blockIdx.x * 128, n0 = blockIdx.y * 128;
  gemm_tile_hi(Qh, (size_t)(b * 2048 + m0), 1024, KtVTh + ((size_t)b << 20), (size_t)n0, 1024, 1024,
               sA, sB, acc);
  int tid = threadIdx.x, l = tid & 63, w = tid >> 6;
  int wm = (w >> 1) * 64, wn = (w & 1) * 64, lr = l & 15, lk = l >> 4;
#pragma unroll
  for (int mi = 0; mi < 4; ++mi)
#pragma unroll
    for (int ni = 0; ni < 4; ++ni)
#pragma unroll
      for (int r = 0; r < 4; ++r) {
        int m = m0 + wm + mi * 16 + lk * 4 + r;
        int n = n0 + wn + ni * 16 + lr;
        y[((size_t)b * 2048 + m) * 1024 + n] = acc[mi][ni][r];
      }
}

// ---- K5: GroupNorm (groups of 32 channels, two-pass) + transposed store out[b][d][t]
__global__ void k_gnorm(const float* __restrict__ y, const float* __restrict__ w,
                        const float* __restrict__ bias, float* __restrict__ out) {
  __shared__ float tile[32][33];
  __shared__ float meanS[32], rstdS[32];
  int t0 = blockIdx.x * 32;
  int g = blockIdx.y;
  int b = blockIdx.z;
  int tid = threadIdx.x;
  int cc = tid & 31, rr = tid >> 5;
#pragma unroll
  for (int it = 0; it < 4; ++it) {
    int r = rr + it * 8;
    tile[r][cc] = y[((size_t)(b * 2048 + t0 + r)) * 1024 + g * 32 + cc];
  }
  __syncthreads();
  if (tid < 32) {
    float s = 0.f;
#pragma unroll
    for (int j = 0; j < 32; ++j) s += tile[tid][j];
    float m = s * (1.f / 32.f);
    float v = 0.f;
#pragma unroll
    for (int j = 0; j < 32; ++j) {
      float d = tile[tid][j] - m;
      v += d * d;
    }
    meanS[tid] = m;
    rstdS[tid] = rsqrtf(v * (1.f / 32.f) + 1e-5f);
  }
  __syncthreads();
#pragma unroll
  for (int it = 0; it < 4; ++it) {
    int idx = tid + it * 256;
    int tl = idx & 31, dd = idx >> 5;
    float val = (tile[tl][dd] - meanS[tl]) * rstdS[tl];
    val = val * w[g * 32 + dd] + bias[g * 32 + dd];
    out[((size_t)(b * 1024 + g * 32 + dd)) * 2048 + t0 + tl] = val;
  }
}

extern "C" void kernel_launch(void* const* d_in, const int* in_sizes, int n_in,
                              void* d_out, int out_size, void* d_ws, size_t ws_size,
                              hipStream_t stream) {
  const float* x = (const float*)d_in[0];
  const float* W = (const float*)d_in[1];
  const float* b_in = (const float*)d_in[2];
  const float* gnw = (const float*)d_in[3];
  const float* gnb = (const float*)d_in[4];
  float* out = (float*)d_out;
  char* ws = (char*)d_ws;

  // Workspace layout (bytes):
  //  R1 (dead after last k_gemm1; KtVT overlaid here after):
  //   [0,        6291456)   WTh
  //   [6291456,  12582912)  WTl
  //   [12582912, 29360128)  xh
  //   [29360128, 46137344)  xl
  //   overlay: KtVTh @ 0 (8388608)
  //  [46137344, 96468992)   qkv_half f32 (4096x3072); overlay: y f32 (8192x1024, 33554432)
  //  [96468992, ...)        Qh, Kth, Vth (3 x 16777216)
  u16* WTh = (u16*)(ws + 0);
  u16* WTl = (u16*)(ws + 6291456);
  u16* xh = (u16*)(ws + 12582912);
  u16* xl = (u16*)(ws + 29360128);
  u16* KtVTh = (u16*)(ws + 0);
  float* qkv = (float*)(ws + 46137344);
  float* y = (float*)(ws + 46137344);
  u16* Qh = (u16*)(ws + 96468992);
  u16* Kth = (u16*)(ws + 96468992 + 16777216);
  u16* Vth = (u16*)(ws + 96468992 + 2 * 16777216);

  k_transW<<<dim3(96, 32), 256, 0, stream>>>(W, WTh, WTl);
  k_splitX<<<32768, 256, 0, stream>>>(x, xh, xl, 8388608);

  for (int h = 0; h < 2; ++h) {
    int row0 = h * 4096;
    k_gemm1<<<dim3(32, 24), 256, 0, stream>>>(xh, xl, WTh, WTl, b_in, qkv, row0);
    k_rope_q<<<8192, 256, 0, stream>>>(qkv, Qh, row0);
    k_ropeT<<<dim3(128, 32), 256, 0, stream>>>(qkv, Kth, row0, 0);
    k_ropeT<<<dim3(128, 32), 256, 0, stream>>>(qkv, Vth, row0, 1);
  }

  k_gemm2<<<dim3(8, 8, 4), 256, 0, stream>>>(Kth, Vth, KtVTh);
  k_gemm3<<<dim3(16, 8, 4), 256, 0, stream>>>(Qh, KtVTh, y);
  k_gnorm<<<dim3(64, 32, 4), 256, 0, stream>>>(y, gnw, gnb, out);
}

// Round 3
// 292.682 us; speedup vs baseline: 1.4673x; 1.1172x over previous
//
#include <hip/hip_runtime.h>

// ActivatedAttention: out = transpose(GroupNorm( relu(rope(Q)) @ [relu(rope(K))^T @ relu(V)] )).
// B=4, T=2048, D=1024. y = Q @ (K^T V)  (no softmax -> associativity).
// gemm1 (x@W): split-bf16, 3 MFMA products, rope/relu/store fused in epilogue.
// gemm2/gemm3: post-ReLU operands are non-negative -> coherent sums -> hi-only bf16.
// Staging: global_load_lds width=16, linear LDS dest, XOR-swizzled global source +
// swizzled ds_read (slot ^= row&7 on [128][64] bf16 buffers) -> 2-way bank alias (free).

typedef unsigned short u16;
typedef __attribute__((ext_vector_type(4))) unsigned short u16x4;
typedef __attribute__((ext_vector_type(8))) unsigned short u16x8;
typedef __attribute__((ext_vector_type(4))) float fx4;
typedef __attribute__((ext_vector_type(8))) __bf16 bfx8;

__device__ __forceinline__ u16 f2bh(float v) {  // f32 -> bf16 RNE
  unsigned u = __float_as_uint(v);
  return (u16)((u + 0x7FFFu + ((u >> 16) & 1u)) >> 16);
}
__device__ __forceinline__ float bh2f(u16 h) {
  return __uint_as_float((unsigned)h << 16);
}
__device__ __forceinline__ void split2(float v, u16& hi, u16& lo) {
  hi = f2bh(v);
  lo = f2bh(v - bh2f(hi));
}
__device__ __forceinline__ fx4 mfma16(bfx8 a, bfx8 b, fx4 c) {
  return __builtin_amdgcn_mfma_f32_16x16x32_bf16(a, b, c, 0, 0, 0);
}

__device__ __forceinline__ void gload16(const u16* g, u16* l) {
  __builtin_amdgcn_global_load_lds(
      (const __attribute__((address_space(1))) unsigned int*)(const void*)g,
      (__attribute__((address_space(3))) unsigned int*)(void*)l, 16, 0, 0);
}

// Swizzled LDS read: buffer is [128 rows][8 slots of 16B]; logical slot q of row r
// lives at physical slot q ^ (r&7).
__device__ __forceinline__ bfx8 ldsw(const u16* lds, int row, int slot) {
  const char* p = (const char*)lds + row * 128 + ((slot ^ (row & 7)) << 4);
  return __builtin_bit_cast(bfx8, *reinterpret_cast<const u16x8*>(p));
}

// Stage combined hi/lo tile: rows rowBase..+127, cols k0..k0+31 of H (slots 0-3) and
// L (slots 4-7). LDS dest linear; source address pre-swizzled so read-side XOR matches.
__device__ __forceinline__ void stage_cmb(const u16* __restrict__ H, const u16* __restrict__ L,
                                          size_t rowBase, int stride, int k0,
                                          u16* lds, int w, int lane) {
#pragma unroll
  for (int i = 0; i < 4; ++i) {
    int c = ((w * 4 + i) << 6) + lane;  // chunk 0..1023
    int r = c >> 3, s = c & 7;
    int t = s ^ (r & 7);                // logical slot stored at physical s
    const u16* src = ((t < 4) ? H : L) + (rowBase + (size_t)r) * (size_t)stride + k0 + ((t & 3) << 3);
    gload16(src, lds + ((w * 4 + i) << 9));
  }
}

// Stage hi-only tile: rows rowBase..+127, cols k0..k0+63 (8 slots).
__device__ __forceinline__ void stage64(const u16* __restrict__ A,
                                        size_t rowBase, int stride, int k0,
                                        u16* lds, int w, int lane) {
#pragma unroll
  for (int i = 0; i < 4; ++i) {
    int c = ((w * 4 + i) << 6) + lane;
    int r = c >> 3, s = c & 7;
    int t = s ^ (r & 7);
    const u16* src = A + (rowBase + (size_t)r) * (size_t)stride + k0 + (t << 3);
    gload16(src, lds + ((w * 4 + i) << 9));
  }
}

// ---- hi-only 128x128 GEMM core, BK=64. A:[M][K], B stored transposed [N][K].
__device__ inline void gemm_core_hi64(const u16* __restrict__ A, size_t aBase, int aStr,
                                      const u16* __restrict__ B, size_t bBase, int bStr, int K,
                                      u16* sA, u16* sB, fx4 acc[4][4], int w, int lane) {
  int wm = (w >> 1) * 64, wn = (w & 1) * 64;
  int lr = lane & 15, lk = lane >> 4;
  for (int k0 = 0; k0 < K; k0 += 64) {
    __syncthreads();
    stage64(A, aBase, aStr, k0, sA, w, lane);
    stage64(B, bBase, bStr, k0, sB, w, lane);
    __syncthreads();
    bfx8 a[8], b[8];
#pragma unroll
    for (int h = 0; h < 2; ++h)
#pragma unroll
      for (int i = 0; i < 4; ++i) {
        a[h * 4 + i] = ldsw(sA, wm + i * 16 + lr, h * 4 + lk);
        b[h * 4 + i] = ldsw(sB, wn + i * 16 + lr, h * 4 + lk);
      }
#pragma unroll
    for (int h = 0; h < 2; ++h)
#pragma unroll
      for (int mi = 0; mi < 4; ++mi)
#pragma unroll
        for (int ni = 0; ni < 4; ++ni)
          acc[mi][ni] = mfma16(a[h * 4 + mi], b[h * 4 + ni], acc[mi][ni]);
  }
}

// ---- K0b: transpose + split W (1024x3072 f32) -> WT[3072][1024] hi/lo bf16
__global__ void k_transW(const float* __restrict__ W, u16* __restrict__ WTh, u16* __restrict__ WTl) {
  __shared__ float tile[32][33];
  int n0 = blockIdx.x * 32, k0 = blockIdx.y * 32;
  int tid = threadIdx.x;
  int c = tid & 31, r4 = tid >> 5;
#pragma unroll
  for (int it = 0; it < 4; ++it) {
    int r = r4 + it * 8;
    tile[r][c] = W[(size_t)(k0 + r) * 3072 + n0 + c];
  }
  __syncthreads();
#pragma unroll
  for (int it = 0; it < 4; ++it) {
    int r = r4 + it * 8;
    u16 hi, lo;
    split2(tile[c][r], hi, lo);
    size_t o = (size_t)(n0 + r) * 1024 + k0 + c;
    WTh[o] = hi;
    WTl[o] = lo;
  }
}

// ---- K0c: split x -> xh/xl (vectorized x4)
__global__ void k_splitX(const float* __restrict__ x, u16* __restrict__ xh, u16* __restrict__ xl) {
  size_t i = (size_t)blockIdx.x * 256 + threadIdx.x;  // over 2097152 float4
  fx4 v = *reinterpret_cast<const fx4*>(x + i * 4);
  u16x4 h, l;
#pragma unroll
  for (int j = 0; j < 4; ++j) {
    u16 hh, ll;
    split2(v[j], hh, ll);
    h[j] = hh;
    l[j] = ll;
  }
  *reinterpret_cast<u16x4*>(xh + i * 4) = h;
  *reinterpret_cast<u16x4*>(xl + i * 4) = l;
}

// ---- G1 fused: [relu(rope(x@W+b))] -> Qh row-major, Kth/Vth transposed [B][D][T]
__global__ __launch_bounds__(256) void k_gemm1f(const u16* __restrict__ xh, const u16* __restrict__ xl,
                                                const u16* __restrict__ WTh, const u16* __restrict__ WTl,
                                                const float* __restrict__ b_in,
                                                u16* __restrict__ Qh, u16* __restrict__ Kth,
                                                u16* __restrict__ Vth) {
  __shared__ u16 sA[128 * 64], sB[128 * 64];
  int bid = blockIdx.x;                      // 1536 blocks, 1536%8==0
  int swz = (bid & 7) * 192 + (bid >> 3);    // XCD-chunked
  int mt = swz & 63, nt = swz >> 6;          // col-major: chunk shares 3 B-panels
  int m0 = mt << 7, n0 = nt << 7;
  int tid = threadIdx.x, lane = tid & 63, w = tid >> 6;
  int wm = (w >> 1) * 64, wn = (w & 1) * 64;
  int lr = lane & 15, lk = lane >> 4;
  fx4 acc[4][4];
#pragma unroll
  for (int i = 0; i < 4; ++i)
#pragma unroll
    for (int j = 0; j < 4; ++j) acc[i][j] = fx4{0.f, 0.f, 0.f, 0.f};

  for (int k0 = 0; k0 < 1024; k0 += 32) {
    __syncthreads();
    stage_cmb(xh, xl, (size_t)m0, 1024, k0, sA, w, lane);
    stage_cmb(WTh, WTl, (size_t)n0, 1024, k0, sB, w, lane);
    __syncthreads();
    bfx8 ah[4], al[4], bh[4], bl[4];
#pragma unroll
    for (int i = 0; i < 4; ++i) {
      ah[i] = ldsw(sA, wm + i * 16 + lr, lk);
      al[i] = ldsw(sA, wm + i * 16 + lr, 4 + lk);
      bh[i] = ldsw(sB, wn + i * 16 + lr, lk);
      bl[i] = ldsw(sB, wn + i * 16 + lr, 4 + lk);
    }
#pragma unroll
    for (int mi = 0; mi < 4; ++mi)
#pragma unroll
      for (int ni = 0; ni < 4; ++ni) {
        acc[mi][ni] = mfma16(ah[mi], bh[ni], acc[mi][ni]);
        acc[mi][ni] = mfma16(ah[mi], bl[ni], acc[mi][ni]);
        acc[mi][ni] = mfma16(al[mi], bh[ni], acc[mi][ni]);
      }
  }

  // Fused epilogue: bias + rope(+shfl pair)/relu + bf16 store.
  int part = n0 >> 10;  // 0=Q, 1=K, 2=V (uniform per block)
  float bv[4];
#pragma unroll
  for (int ni = 0; ni < 4; ++ni) bv[ni] = b_in[n0 + wn + ni * 16 + lr];
#pragma unroll
  for (int mi = 0; mi < 4; ++mi)
#pragma unroll
    for (int ni = 0; ni < 4; ++ni)
#pragma unroll
      for (int r = 0; r < 4; ++r) {
        float v = acc[mi][ni][r] + bv[ni];
        int m = m0 + wm + mi * 16 + lk * 4 + r;
        int n = n0 + wn + ni * 16 + lr;
        int d = n - (part << 10);
        int bb = m >> 11, t = m & 2047;
        if (part == 2) {
          Vth[((size_t)((bb << 10) + d) << 11) + t] = f2bh(fmaxf(v, 0.f));
        } else {
          float p = __shfl_xor(v, 1);  // partner column (n^1), same (mi,ni,r)
          float invf = exp2f(-(float)(d >> 1) * (13.287712379549449f / 512.f));  // 10000^(-i/512)
          float ang = (float)t * invf, s, c;
          sincosf(ang, &s, &c);
          // even d: v*c - p*s ; odd d: v*c + p*s
          float o = fmaxf(v * c + p * ((d & 1) ? s : -s), 0.f);
          if (part == 0)
            Qh[((size_t)m << 10) + d] = f2bh(o);
          else
            Kth[((size_t)((bb << 10) + d) << 11) + t] = f2bh(o);
        }
      }
}

// ---- G2: KtVT[b][n][m] = (K^T V)[m][n], hi-only bf16 out
__global__ __launch_bounds__(256) void k_gemm2(const u16* __restrict__ Kth, const u16* __restrict__ Vth,
                                               u16* __restrict__ KtVTh) {
  __shared__ u16 sA[128 * 64], sB[128 * 64];
  fx4 acc[4][4];
#pragma unroll
  for (int i = 0; i < 4; ++i)
#pragma unroll
    for (int j = 0; j < 4; ++j) acc[i][j] = fx4{0.f, 0.f, 0.f, 0.f};
  int b = blockIdx.z;
  int m0 = blockIdx.x << 7, n0 = blockIdx.y << 7;
  int tid = threadIdx.x, lane = tid & 63, w = tid >> 6;
  const u16* Ab = Kth + ((size_t)b << 21);
  const u16* Bb = Vth + ((size_t)b << 21);
  gemm_core_hi64(Ab, (size_t)m0, 2048, Bb, (size_t)n0, 2048, 2048, sA, sB, acc, w, lane);
  int wm = (w >> 1) * 64, wn = (w & 1) * 64, lr = lane & 15, lk = lane >> 4;
#pragma unroll
  for (int mi = 0; mi < 4; ++mi)
#pragma unroll
    for (int ni = 0; ni < 4; ++ni)
#pragma unroll
      for (int r = 0; r < 4; ++r) {
        int m = m0 + wm + mi * 16 + lk * 4 + r;
        int n = n0 + wn + ni * 16 + lr;
        KtVTh[((size_t)b << 20) + ((size_t)n << 10) + m] = f2bh(acc[mi][ni][r]);
      }
}

// ---- G3: y[b][t][n] = Q[b] @ KtV[b]  (f32 out)
__global__ __launch_bounds__(256) void k_gemm3(const u16* __restrict__ Qh, const u16* __restrict__ KtVTh,
                                               float* __restrict__ y) {
  __shared__ u16 sA[128 * 64], sB[128 * 64];
  fx4 acc[4][4];
#pragma unroll
  for (int i = 0; i < 4; ++i)
#pragma unroll
    for (int j = 0; j < 4; ++j) acc[i][j] = fx4{0.f, 0.f, 0.f, 0.f};
  int b = blockIdx.z;
  int m0 = blockIdx.x << 7, n0 = blockIdx.y << 7;
  int tid = threadIdx.x, lane = tid & 63, w = tid >> 6;
  gemm_core_hi64(Qh, (size_t)(b * 2048 + m0), 1024, KtVTh + ((size_t)b << 20), (size_t)n0, 1024, 1024,
                 sA, sB, acc, w, lane);
  int wm = (w >> 1) * 64, wn = (w & 1) * 64, lr = lane & 15, lk = lane >> 4;
#pragma unroll
  for (int mi = 0; mi < 4; ++mi)
#pragma unroll
    for (int ni = 0; ni < 4; ++ni)
#pragma unroll
      for (int r = 0; r < 4; ++r) {
        int m = m0 + wm + mi * 16 + lk * 4 + r;
        int n = n0 + wn + ni * 16 + lr;
        y[((size_t)(b * 2048 + m) << 10) + n] = acc[mi][ni][r];
      }
}

// ---- K5: GroupNorm (32-ch groups, two-pass) + transposed store out[b][d][t]
__global__ void k_gnorm(const float* __restrict__ y, const float* __restrict__ w,
                        const float* __restrict__ bias, float* __restrict__ out) {
  __shared__ float tile[32][33];
  __shared__ float meanS[32], rstdS[32];
  int t0 = blockIdx.x * 32;
  int g = blockIdx.y;
  int b = blockIdx.z;
  int tid = threadIdx.x;
  int cc = tid & 31, rr = tid >> 5;
#pragma unroll
  for (int it = 0; it < 4; ++it) {
    int r = rr + it * 8;
    tile[r][cc] = y[((size_t)(b * 2048 + t0 + r)) * 1024 + g * 32 + cc];
  }
  __syncthreads();
  if (tid < 32) {
    float s = 0.f;
#pragma unroll
    for (int j = 0; j < 32; ++j) s += tile[tid][j];
    float m = s * (1.f / 32.f);
    float v = 0.f;
#pragma unroll
    for (int j = 0; j < 32; ++j) {
      float dd = tile[tid][j] - m;
      v += dd * dd;
    }
    meanS[tid] = m;
    rstdS[tid] = rsqrtf(v * (1.f / 32.f) + 1e-5f);
  }
  __syncthreads();
#pragma unroll
  for (int it = 0; it < 4; ++it) {
    int idx = tid + it * 256;
    int tl = idx & 31, dd = idx >> 5;
    float val = (tile[tl][dd] - meanS[tl]) * rstdS[tl];
    val = val * w[g * 32 + dd] + bias[g * 32 + dd];
    out[((size_t)(b * 1024 + g * 32 + dd)) * 2048 + t0 + tl] = val;
  }
}

extern "C" void kernel_launch(void* const* d_in, const int* in_sizes, int n_in,
                              void* d_out, int out_size, void* d_ws, size_t ws_size,
                              hipStream_t stream) {
  const float* x = (const float*)d_in[0];
  const float* W = (const float*)d_in[1];
  const float* b_in = (const float*)d_in[2];
  const float* gnw = (const float*)d_in[3];
  const float* gnb = (const float*)d_in[4];
  float* out = (float*)d_out;
  char* ws = (char*)d_ws;

  // Workspace (bytes): xh@0(16M), xl@16M, WTh@32M(6M), WTl@38M, Qh@44M(16M),
  // Kth@60M, Vth@76M, KtVTh@92M(8M), y@100M(32M). Total ~132MB.
  u16* xh = (u16*)(ws + 0);
  u16* xl = (u16*)(ws + 16777216);
  u16* WTh = (u16*)(ws + 33554432);
  u16* WTl = (u16*)(ws + 39845888);
  u16* Qh = (u16*)(ws + 46137344);
  u16* Kth = (u16*)(ws + 62914560);
  u16* Vth = (u16*)(ws + 79691776);
  u16* KtVTh = (u16*)(ws + 96468992);
  float* y = (float*)(ws + 104857600);

  k_transW<<<dim3(96, 32), 256, 0, stream>>>(W, WTh, WTl);
  k_splitX<<<8192, 256, 0, stream>>>(x, xh, xl);
  k_gemm1f<<<1536, 256, 0, stream>>>(xh, xl, WTh, WTl, b_in, Qh, Kth, Vth);
  k_gemm2<<<dim3(8, 8, 4), 256, 0, stream>>>(Kth, Vth, KtVTh);
  k_gemm3<<<dim3(16, 8, 4), 256, 0, stream>>>(Qh, KtVTh, y);
  k_gnorm<<<dim3(64, 32, 4), 256, 0, stream>>>(y, gnw, gnb, out);
}

// Round 4
// 190.193 us; speedup vs baseline: 2.2579x; 1.5389x over previous
//
#include <hip/hip_runtime.h>

// ActivatedAttention: out = transpose(GroupNorm( relu(rope(Q)) @ [relu(rope(K))^T @ relu(V)] )).
// B=4, T=2048, D=1024. y = Q @ (K^T V)  (no softmax -> associativity).
// All GEMMs hi-only bf16 (error budget: absmax ~0.03 vs threshold 0.0728; dominated by
// the unavoidable bf16 rounding of Q/K/V; gemm1 hi-only adds ~sqrt(2)x, validated vs bench).
// gemm1 fuses rope/relu/bf16-store; gemm3 fuses GroupNorm + transposed store.
// Staging: global_load_lds width=16, linear LDS dest, XOR-swizzled global source +
// swizzled ds_read (slot ^= row&7 on [128][64] bf16 buffers) -> conflict-free.

typedef unsigned short u16;
typedef __attribute__((ext_vector_type(8))) unsigned short u16x8;
typedef __attribute__((ext_vector_type(4))) float fx4;
typedef __attribute__((ext_vector_type(8))) __bf16 bfx8;

__device__ __forceinline__ u16 f2bh(float v) {  // f32 -> bf16 RNE
  unsigned u = __float_as_uint(v);
  return (u16)((u + 0x7FFFu + ((u >> 16) & 1u)) >> 16);
}
__device__ __forceinline__ fx4 mfma16(bfx8 a, bfx8 b, fx4 c) {
  return __builtin_amdgcn_mfma_f32_16x16x32_bf16(a, b, c, 0, 0, 0);
}

__device__ __forceinline__ void gload16(const u16* g, u16* l) {
  __builtin_amdgcn_global_load_lds(
      (const __attribute__((address_space(1))) unsigned int*)(const void*)g,
      (__attribute__((address_space(3))) unsigned int*)(void*)l, 16, 0, 0);
}

// Swizzled LDS read: buffer is [128 rows][8 slots of 16B]; logical slot q of row r
// lives at physical slot q ^ (r&7).
__device__ __forceinline__ bfx8 ldsw(const u16* lds, int row, int slot) {
  const char* p = (const char*)lds + row * 128 + ((slot ^ (row & 7)) << 4);
  return __builtin_bit_cast(bfx8, *reinterpret_cast<const u16x8*>(p));
}

// Stage tile rows rowBase..+127, cols k0..k0+63 (8 slots). Linear LDS dest,
// pre-swizzled global source so the read-side XOR matches (rule: both sides or neither).
__device__ __forceinline__ void stage64(const u16* __restrict__ A,
                                        size_t rowBase, int stride, int k0,
                                        u16* lds, int w, int lane) {
#pragma unroll
  for (int i = 0; i < 4; ++i) {
    int c = ((w * 4 + i) << 6) + lane;  // chunk 0..1023
    int r = c >> 3, s = c & 7;
    int t = s ^ (r & 7);
    const u16* src = A + (rowBase + (size_t)r) * (size_t)stride + k0 + (t << 3);
    gload16(src, lds + ((w * 4 + i) << 9));
  }
}

// ---- hi-only 128x128 GEMM core, BK=64. A:[M][K], B stored transposed [N][K].
__device__ inline void gemm_core_hi64(const u16* __restrict__ A, size_t aBase, int aStr,
                                      const u16* __restrict__ B, size_t bBase, int bStr, int K,
                                      u16* sA, u16* sB, fx4 acc[4][4], int w, int lane) {
  int wm = (w >> 1) * 64, wn = (w & 1) * 64;
  int lr = lane & 15, lk = lane >> 4;
  for (int k0 = 0; k0 < K; k0 += 64) {
    __syncthreads();
    stage64(A, aBase, aStr, k0, sA, w, lane);
    stage64(B, bBase, bStr, k0, sB, w, lane);
    __syncthreads();
    bfx8 a[8], b[8];
#pragma unroll
    for (int h = 0; h < 2; ++h)
#pragma unroll
      for (int i = 0; i < 4; ++i) {
        a[h * 4 + i] = ldsw(sA, wm + i * 16 + lr, h * 4 + lk);
        b[h * 4 + i] = ldsw(sB, wn + i * 16 + lr, h * 4 + lk);
      }
#pragma unroll
    for (int h = 0; h < 2; ++h)
#pragma unroll
      for (int mi = 0; mi < 4; ++mi)
#pragma unroll
        for (int ni = 0; ni < 4; ++ni)
          acc[mi][ni] = mfma16(a[h * 4 + mi], b[h * 4 + ni], acc[mi][ni]);
  }
}

// ---- K0b: transpose W (1024x3072 f32) -> WT[3072][1024] bf16
__global__ void k_transW(const float* __restrict__ W, u16* __restrict__ WTh) {
  __shared__ float tile[32][33];
  int n0 = blockIdx.x * 32, k0 = blockIdx.y * 32;
  int tid = threadIdx.x;
  int c = tid & 31, r4 = tid >> 5;
#pragma unroll
  for (int it = 0; it < 4; ++it) {
    int r = r4 + it * 8;
    tile[r][c] = W[(size_t)(k0 + r) * 3072 + n0 + c];
  }
  __syncthreads();
#pragma unroll
  for (int it = 0; it < 4; ++it) {
    int r = r4 + it * 8;
    WTh[(size_t)(n0 + r) * 1024 + k0 + c] = f2bh(tile[c][r]);
  }
}

// ---- K0c: cast x -> bf16 (8 elems/thread)
__global__ void k_castX(const float* __restrict__ x, u16* __restrict__ xh) {
  size_t i = ((size_t)blockIdx.x * 256 + threadIdx.x) * 8;
  fx4 v0 = *reinterpret_cast<const fx4*>(x + i);
  fx4 v1 = *reinterpret_cast<const fx4*>(x + i + 4);
  u16x8 h;
#pragma unroll
  for (int j = 0; j < 4; ++j) {
    h[j] = f2bh(v0[j]);
    h[4 + j] = f2bh(v1[j]);
  }
  *reinterpret_cast<u16x8*>(xh + i) = h;
}

// ---- G1 fused: relu(rope(x@W+b)) -> Qh row-major, Kth/Vth transposed [B][D][T]
__global__ __launch_bounds__(256) void k_gemm1f(const u16* __restrict__ xh,
                                                const u16* __restrict__ WTh,
                                                const float* __restrict__ b_in,
                                                u16* __restrict__ Qh, u16* __restrict__ Kth,
                                                u16* __restrict__ Vth) {
  __shared__ u16 sA[128 * 64], sB[128 * 64];
  // XCD-chunked swizzle: 1536 blocks = 8 XCD x (8 mt x 24 nt), mt-fastest within chunk.
  // Per-XCD A slice = 8 mt x 128 rows x 2KB = 2MB (L2-resident); B panels shared in time.
  int bid = blockIdx.x;
  int xcd = bid & 7, idx = bid >> 3;
  int mt = (xcd << 3) + (idx & 7), nt = idx >> 3;
  int m0 = mt << 7, n0 = nt << 7;
  int tid = threadIdx.x, lane = tid & 63, w = tid >> 6;
  int wm = (w >> 1) * 64, wn = (w & 1) * 64;
  int lr = lane & 15, lk = lane >> 4;
  fx4 acc[4][4];
#pragma unroll
  for (int i = 0; i < 4; ++i)
#pragma unroll
    for (int j = 0; j < 4; ++j) acc[i][j] = fx4{0.f, 0.f, 0.f, 0.f};

  gemm_core_hi64(xh, (size_t)m0, 1024, WTh, (size_t)n0, 1024, 1024, sA, sB, acc, w, lane);

  // Fused epilogue: bias + rope(+shfl pair)/relu + bf16 store.
  int part = n0 >> 10;  // 0=Q, 1=K, 2=V (uniform per block)
  float bv[4];
#pragma unroll
  for (int ni = 0; ni < 4; ++ni) bv[ni] = b_in[n0 + wn + ni * 16 + lr];
#pragma unroll
  for (int mi = 0; mi < 4; ++mi)
#pragma unroll
    for (int ni = 0; ni < 4; ++ni)
#pragma unroll
      for (int r = 0; r < 4; ++r) {
        float v = acc[mi][ni][r] + bv[ni];
        int m = m0 + wm + mi * 16 + lk * 4 + r;
        int n = n0 + wn + ni * 16 + lr;
        int d = n - (part << 10);
        int bb = m >> 11, t = m & 2047;
        if (part == 2) {
          Vth[((size_t)((bb << 10) + d) << 11) + t] = f2bh(fmaxf(v, 0.f));
        } else {
          float p = __shfl_xor(v, 1);  // partner column (n^1), same (mi,ni,r)
          float invf = exp2f(-(float)(d >> 1) * (13.287712379549449f / 512.f));  // 10000^(-i/512)
          float ang = (float)t * invf, s, c;
          sincosf(ang, &s, &c);
          float o = fmaxf(v * c + p * ((d & 1) ? s : -s), 0.f);  // even d: vc-ps, odd: vc+ps
          if (part == 0)
            Qh[((size_t)m << 10) + d] = f2bh(o);
          else
            Kth[((size_t)((bb << 10) + d) << 11) + t] = f2bh(o);
        }
      }
}

// ---- G2: KtVT[b][n][m] = (K^T V)[m][n], bf16 out
__global__ __launch_bounds__(256) void k_gemm2(const u16* __restrict__ Kth, const u16* __restrict__ Vth,
                                               u16* __restrict__ KtVTh) {
  __shared__ u16 sA[128 * 64], sB[128 * 64];
  fx4 acc[4][4];
#pragma unroll
  for (int i = 0; i < 4; ++i)
#pragma unroll
    for (int j = 0; j < 4; ++j) acc[i][j] = fx4{0.f, 0.f, 0.f, 0.f};
  int b = blockIdx.z;
  int m0 = blockIdx.x << 7, n0 = blockIdx.y << 7;
  int tid = threadIdx.x, lane = tid & 63, w = tid >> 6;
  const u16* Ab = Kth + ((size_t)b << 21);
  const u16* Bb = Vth + ((size_t)b << 21);
  gemm_core_hi64(Ab, (size_t)m0, 2048, Bb, (size_t)n0, 2048, 2048, sA, sB, acc, w, lane);
  int wm = (w >> 1) * 64, wn = (w & 1) * 64, lr = lane & 15, lk = lane >> 4;
#pragma unroll
  for (int mi = 0; mi < 4; ++mi)
#pragma unroll
    for (int ni = 0; ni < 4; ++ni)
#pragma unroll
      for (int r = 0; r < 4; ++r) {
        int m = m0 + wm + mi * 16 + lk * 4 + r;
        int n = n0 + wn + ni * 16 + lr;
        KtVTh[((size_t)b << 20) + ((size_t)n << 10) + m] = f2bh(acc[mi][ni][r]);
      }
}

// ---- G3 fused: y = Q @ KtV, then GroupNorm(32-ch groups) + transposed store out[b][d][t].
// Each 128-wide n-tile holds whole groups; a row's 32 group values live in 2 regs x 16
// lanes (lr) -> two-pass mean/var via __shfl_xor masks 1,2,4,8 (stays within lk group).
__global__ __launch_bounds__(256) void k_gemm3g(const u16* __restrict__ Qh, const u16* __restrict__ KtVTh,
                                                const float* __restrict__ gw, const float* __restrict__ gb,
                                                float* __restrict__ out) {
  __shared__ u16 sA[128 * 64], sB[128 * 64];
  fx4 acc[4][4];
#pragma unroll
  for (int i = 0; i < 4; ++i)
#pragma unroll
    for (int j = 0; j < 4; ++j) acc[i][j] = fx4{0.f, 0.f, 0.f, 0.f};
  int b = blockIdx.z;
  int m0 = blockIdx.x << 7, n0 = blockIdx.y << 7;
  int tid = threadIdx.x, lane = tid & 63, w = tid >> 6;
  gemm_core_hi64(Qh, (size_t)(b * 2048 + m0), 1024, KtVTh + ((size_t)b << 20), (size_t)n0, 1024, 1024,
                 sA, sB, acc, w, lane);
  int wm = (w >> 1) * 64, wn = (w & 1) * 64, lr = lane & 15, lk = lane >> 4;
  float wv[4], bvv[4];
#pragma unroll
  for (int ni = 0; ni < 4; ++ni) {
    int n = n0 + wn + ni * 16 + lr;
    wv[ni] = gw[n];
    bvv[ni] = gb[n];
  }
#pragma unroll
  for (int mi = 0; mi < 4; ++mi) {
    fx4 o0, o1, o2, o3;
#pragma unroll
    for (int r = 0; r < 4; ++r) {
      float v0 = acc[mi][0][r], v1 = acc[mi][1][r], v2 = acc[mi][2][r], v3 = acc[mi][3][r];
      float sA2 = v0 + v1, sB2 = v2 + v3;
#pragma unroll
      for (int mk = 1; mk <= 8; mk <<= 1) {
        sA2 += __shfl_xor(sA2, mk);
        sB2 += __shfl_xor(sB2, mk);
      }
      float mA = sA2 * (1.f / 32.f), mB = sB2 * (1.f / 32.f);
      float dA = (v0 - mA) * (v0 - mA) + (v1 - mA) * (v1 - mA);
      float dB = (v2 - mB) * (v2 - mB) + (v3 - mB) * (v3 - mB);
#pragma unroll
      for (int mk = 1; mk <= 8; mk <<= 1) {
        dA += __shfl_xor(dA, mk);
        dB += __shfl_xor(dB, mk);
      }
      float rA = rsqrtf(dA * (1.f / 32.f) + 1e-5f);
      float rB = rsqrtf(dB * (1.f / 32.f) + 1e-5f);
      o0[r] = (v0 - mA) * rA * wv[0] + bvv[0];
      o1[r] = (v1 - mA) * rA * wv[1] + bvv[1];
      o2[r] = (v2 - mB) * rB * wv[2] + bvv[2];
      o3[r] = (v3 - mB) * rB * wv[3] + bvv[3];
    }
    int mbase = m0 + wm + mi * 16 + lk * 4;  // t index, 16B-aligned
#pragma unroll
    for (int ni = 0; ni < 4; ++ni) {
      int n = n0 + wn + ni * 16 + lr;
      fx4 ov = (ni == 0) ? o0 : (ni == 1) ? o1 : (ni == 2) ? o2 : o3;
      *reinterpret_cast<fx4*>(out + (((size_t)(b << 10) + n) << 11) + mbase) = ov;
    }
  }
}

extern "C" void kernel_launch(void* const* d_in, const int* in_sizes, int n_in,
                              void* d_out, int out_size, void* d_ws, size_t ws_size,
                              hipStream_t stream) {
  const float* x = (const float*)d_in[0];
  const float* W = (const float*)d_in[1];
  const float* b_in = (const float*)d_in[2];
  const float* gnw = (const float*)d_in[3];
  const float* gnb = (const float*)d_in[4];
  float* out = (float*)d_out;
  char* ws = (char*)d_ws;

  // Workspace (bytes): xh@0(16M), WTh@16M(6M), Qh@22.5M(16M), Kth(16M), Vth(16M), KtVTh(8M).
  u16* xh = (u16*)(ws + 0);
  u16* WTh = (u16*)(ws + 16777216);
  u16* Qh = (u16*)(ws + 23068672);
  u16* Kth = (u16*)(ws + 39845888);
  u16* Vth = (u16*)(ws + 56623104);
  u16* KtVTh = (u16*)(ws + 73400320);

  k_transW<<<dim3(96, 32), 256, 0, stream>>>(W, WTh);
  k_castX<<<4096, 256, 0, stream>>>(x, xh);
  k_gemm1f<<<1536, 256, 0, stream>>>(xh, WTh, b_in, Qh, Kth, Vth);
  k_gemm2<<<dim3(8, 8, 4), 256, 0, stream>>>(Kth, Vth, KtVTh);
  k_gemm3g<<<dim3(16, 8, 4), 256, 0, stream>>>(Qh, KtVTh, gnw, gnb, out);
}

// Round 5
// 166.102 us; speedup vs baseline: 2.5854x; 1.1450x over previous
//
#include <hip/hip_runtime.h>

// ActivatedAttention: out = transpose(GroupNorm( relu(rope(Q)) @ [relu(rope(K))^T @ relu(V)] )).
// B=4, T=2048, D=1024. y = Q @ (K^T V)  (no softmax -> associativity).
// All GEMMs hi-only bf16 (absmax 0.0234 vs threshold 0.0728, bench-validated).
// gemm1 fuses rope/relu/bf16-store (cos/sin from precomputed tables, stores vectorized
// via LDS transpose tile); gemm3 fuses GroupNorm + transposed store.
// Staging: global_load_lds width=16, linear LDS dest, XOR-swizzled global source +
// swizzled ds_read (slot ^= row&7 on [128][64] bf16 buffers) -> conflict-free.

typedef unsigned short u16;
typedef __attribute__((ext_vector_type(8))) unsigned short u16x8;
typedef __attribute__((ext_vector_type(4))) float fx4;
typedef __attribute__((ext_vector_type(8))) __bf16 bfx8;

#define TP 129  // epilogue f32 tile pitch

__device__ __forceinline__ u16 f2bh(float v) {  // f32 -> bf16 RNE
  unsigned u = __float_as_uint(v);
  return (u16)((u + 0x7FFFu + ((u >> 16) & 1u)) >> 16);
}
__device__ __forceinline__ fx4 mfma16(bfx8 a, bfx8 b, fx4 c) {
  return __builtin_amdgcn_mfma_f32_16x16x32_bf16(a, b, c, 0, 0, 0);
}

__device__ __forceinline__ void gload16(const u16* g, u16* l) {
  __builtin_amdgcn_global_load_lds(
      (const __attribute__((address_space(1))) unsigned int*)(const void*)g,
      (__attribute__((address_space(3))) unsigned int*)(void*)l, 16, 0, 0);
}

// Swizzled LDS read: buffer is [128 rows][8 slots of 16B]; logical slot q of row r
// lives at physical slot q ^ (r&7).
__device__ __forceinline__ bfx8 ldsw(const u16* lds, int row, int slot) {
  const char* p = (const char*)lds + row * 128 + ((slot ^ (row & 7)) << 4);
  return __builtin_bit_cast(bfx8, *reinterpret_cast<const u16x8*>(p));
}

// Stage tile rows rowBase..+127, cols k0..k0+63 (8 slots). Linear LDS dest,
// pre-swizzled global source so the read-side XOR matches (both-sides-or-neither).
__device__ __forceinline__ void stage64(const u16* __restrict__ A,
                                        size_t rowBase, int stride, int k0,
                                        u16* lds, int w, int lane) {
#pragma unroll
  for (int i = 0; i < 4; ++i) {
    int c = ((w * 4 + i) << 6) + lane;  // chunk 0..1023
    int r = c >> 3, s = c & 7;
    int t = s ^ (r & 7);
    const u16* src = A + (rowBase + (size_t)r) * (size_t)stride + k0 + (t << 3);
    gload16(src, lds + ((w * 4 + i) << 9));
  }
}

// ---- hi-only 128x128 GEMM core, BK=64. A:[M][K], B stored transposed [N][K].
__device__ inline void gemm_core_hi64(const u16* __restrict__ A, size_t aBase, int aStr,
                                      const u16* __restrict__ B, size_t bBase, int bStr, int K,
                                      u16* sA, u16* sB, fx4 acc[4][4], int w, int lane) {
  int wm = (w >> 1) * 64, wn = (w & 1) * 64;
  int lr = lane & 15, lk = lane >> 4;
  for (int k0 = 0; k0 < K; k0 += 64) {
    __syncthreads();
    stage64(A, aBase, aStr, k0, sA, w, lane);
    stage64(B, bBase, bStr, k0, sB, w, lane);
    __syncthreads();
    bfx8 a[8], b[8];
#pragma unroll
    for (int h = 0; h < 2; ++h)
#pragma unroll
      for (int i = 0; i < 4; ++i) {
        a[h * 4 + i] = ldsw(sA, wm + i * 16 + lr, h * 4 + lk);
        b[h * 4 + i] = ldsw(sB, wn + i * 16 + lr, h * 4 + lk);
      }
#pragma unroll
    for (int h = 0; h < 2; ++h)
#pragma unroll
      for (int mi = 0; mi < 4; ++mi)
#pragma unroll
        for (int ni = 0; ni < 4; ++ni)
          acc[mi][ni] = mfma16(a[h * 4 + mi], b[h * 4 + ni], acc[mi][ni]);
  }
}

// ---- K0a: rope cos/sin tables. y=0: tabTI[t][i]; y=1: tabIT[i][t]. float2(cos,sin).
__global__ void k_ropetab(float2* __restrict__ tabTI, float2* __restrict__ tabIT) {
  int idx = blockIdx.x * 256 + threadIdx.x;  // 1M entries
  int t, i;
  if (blockIdx.y == 0) {
    t = idx >> 9;
    i = idx & 511;
  } else {
    i = idx >> 11;
    t = idx & 2047;
  }
  float invf = exp2f(-(float)i * (13.287712379549449f / 512.f));  // 10000^(-i/512)
  float ang = (float)t * invf, s, c;
  sincosf(ang, &s, &c);
  if (blockIdx.y == 0)
    tabTI[idx] = make_float2(c, s);
  else
    tabIT[idx] = make_float2(c, s);
}

// ---- K0b: transpose W (1024x3072 f32) -> WT[3072][1024] bf16
__global__ void k_transW(const float* __restrict__ W, u16* __restrict__ WTh) {
  __shared__ float tile[32][33];
  int n0 = blockIdx.x * 32, k0 = blockIdx.y * 32;
  int tid = threadIdx.x;
  int c = tid & 31, r4 = tid >> 5;
#pragma unroll
  for (int it = 0; it < 4; ++it) {
    int r = r4 + it * 8;
    tile[r][c] = W[(size_t)(k0 + r) * 3072 + n0 + c];
  }
  __syncthreads();
#pragma unroll
  for (int it = 0; it < 4; ++it) {
    int r = r4 + it * 8;
    WTh[(size_t)(n0 + r) * 1024 + k0 + c] = f2bh(tile[c][r]);
  }
}

// ---- K0c: cast x -> bf16 (8 elems/thread)
__global__ void k_castX(const float* __restrict__ x, u16* __restrict__ xh) {
  size_t i = ((size_t)blockIdx.x * 256 + threadIdx.x) * 8;
  fx4 v0 = *reinterpret_cast<const fx4*>(x + i);
  fx4 v1 = *reinterpret_cast<const fx4*>(x + i + 4);
  u16x8 h;
#pragma unroll
  for (int j = 0; j < 4; ++j) {
    h[j] = f2bh(v0[j]);
    h[4 + j] = f2bh(v1[j]);
  }
  *reinterpret_cast<u16x8*>(xh + i) = h;
}

// ---- G1 fused: relu(rope(x@W+b)) -> Qh row-major, Kth/Vth transposed [B][D][T]
__global__ __launch_bounds__(256) void k_gemm1f(const u16* __restrict__ xh,
                                                const u16* __restrict__ WTh,
                                                const float* __restrict__ b_in,
                                                const float2* __restrict__ tabTI,
                                                const float2* __restrict__ tabIT,
                                                u16* __restrict__ Qh, u16* __restrict__ Kth,
                                                u16* __restrict__ Vth) {
  __shared__ __align__(16) float shbuf[128 * TP];  // 66KB: sA+sB (32KB) alias the front
  u16* sA = (u16*)shbuf;
  u16* sB = sA + 128 * 64;
  // XCD-chunked swizzle: 1536 blocks = 8 XCD x (8 mt x 24 nt), mt-fastest within chunk.
  // Per-XCD A slice = 8x128 rows x 2KB = 2MB (L2-resident); B panels shared in time.
  int bid = blockIdx.x;
  int xcd = bid & 7, idx = bid >> 3;
  int mt = (xcd << 3) + (idx & 7), nt = idx >> 3;
  int m0 = mt << 7, n0 = nt << 7;
  int tid = threadIdx.x, lane = tid & 63, w = tid >> 6;
  int wm = (w >> 1) * 64, wn = (w & 1) * 64;
  int lr = lane & 15, lk = lane >> 4;
  fx4 acc[4][4];
#pragma unroll
  for (int i = 0; i < 4; ++i)
#pragma unroll
    for (int j = 0; j < 4; ++j) acc[i][j] = fx4{0.f, 0.f, 0.f, 0.f};

  gemm_core_hi64(xh, (size_t)m0, 1024, WTh, (size_t)n0, 1024, 1024, sA, sB, acc, w, lane);

  // ---- Epilogue: acc+bias -> f32 LDS tile [n_local][m_local], then store in
  // output-order with vectorized u16x8 stores + table-based rope.
  float bv[4];
#pragma unroll
  for (int ni = 0; ni < 4; ++ni) bv[ni] = b_in[n0 + wn + ni * 16 + lr];
  __syncthreads();  // all LDS reads of sA/sB done before overwrite
#pragma unroll
  for (int mi = 0; mi < 4; ++mi)
#pragma unroll
    for (int ni = 0; ni < 4; ++ni)
#pragma unroll
      for (int r = 0; r < 4; ++r)
        shbuf[(wn + ni * 16 + lr) * TP + wm + mi * 16 + lk * 4 + r] = acc[mi][ni][r] + bv[ni];
  __syncthreads();

  int part = n0 >> 10;       // 0=Q, 1=K, 2=V (uniform per block)
  int d0 = n0 - (part << 10);
  int bb = m0 >> 11, tb = m0 & 2047;  // 128-row tiles never cross batch boundary
  int rl0 = tid >> 4;        // row within tile (per pass: +16)
  int cc = (tid & 15) * 8;   // 8-elem column chunk

  if (part == 2) {           // V: relu only, store [d][t]
#pragma unroll
    for (int pass = 0; pass < 8; ++pass) {
      int rl = rl0 + pass * 16;
      u16x8 o;
#pragma unroll
      for (int j = 0; j < 8; ++j) o[j] = f2bh(fmaxf(shbuf[rl * TP + cc + j], 0.f));
      *reinterpret_cast<u16x8*>(Vth + (((size_t)(bb << 10) + d0 + rl) << 11) + tb + cc) = o;
    }
  } else if (part == 1) {    // K: rope (rows d, d^1) + relu, store [d][t]
#pragma unroll
    for (int pass = 0; pass < 8; ++pass) {
      int rl = rl0 + pass * 16;
      int d = d0 + rl;
      const float2* tp = tabIT + ((size_t)(d >> 1) << 11) + tb + cc;
      const float* e = shbuf + (rl & ~1) * TP + cc;   // even row
      const float* oo = shbuf + (rl | 1) * TP + cc;   // odd row
      int isOdd = d & 1;
      u16x8 o;
#pragma unroll
      for (int j = 0; j < 8; ++j) {
        float2 cs = tp[j];
        float x1 = e[j], x2 = oo[j];
        float v = isOdd ? (x1 * cs.y + x2 * cs.x) : (x1 * cs.x - x2 * cs.y);
        o[j] = f2bh(fmaxf(v, 0.f));
      }
      *reinterpret_cast<u16x8*>(Kth + (((size_t)(bb << 10) + d) << 11) + tb + cc) = o;
    }
  } else {                   // Q: rope along d, store [m][d]
#pragma unroll
    for (int pass = 0; pass < 8; ++pass) {
      int rl = rl0 + pass * 16;  // m_local
      int m = m0 + rl, t = m & 2047;
      const float2* tp = tabTI + ((size_t)t << 9) + ((d0 + cc) >> 1);
      u16x8 o;
#pragma unroll
      for (int jp = 0; jp < 4; ++jp) {
        float x1 = shbuf[(cc + 2 * jp) * TP + rl];
        float x2 = shbuf[(cc + 2 * jp + 1) * TP + rl];
        float2 cs = tp[jp];
        o[2 * jp] = f2bh(fmaxf(x1 * cs.x - x2 * cs.y, 0.f));
        o[2 * jp + 1] = f2bh(fmaxf(x1 * cs.y + x2 * cs.x, 0.f));
      }
      *reinterpret_cast<u16x8*>(Qh + ((size_t)m << 10) + d0 + cc) = o;
    }
  }
}

// ---- G2: KtVT[b][n][m] = (K^T V)[m][n], bf16 out
__global__ __launch_bounds__(256) void k_gemm2(const u16* __restrict__ Kth, const u16* __restrict__ Vth,
                                               u16* __restrict__ KtVTh) {
  __shared__ u16 sA[128 * 64], sB[128 * 64];
  fx4 acc[4][4];
#pragma unroll
  for (int i = 0; i < 4; ++i)
#pragma unroll
    for (int j = 0; j < 4; ++j) acc[i][j] = fx4{0.f, 0.f, 0.f, 0.f};
  int b = blockIdx.z;
  int m0 = blockIdx.x << 7, n0 = blockIdx.y << 7;
  int tid = threadIdx.x, lane = tid & 63, w = tid >> 6;
  const u16* Ab = Kth + ((size_t)b << 21);
  const u16* Bb = Vth + ((size_t)b << 21);
  gemm_core_hi64(Ab, (size_t)m0, 2048, Bb, (size_t)n0, 2048, 2048, sA, sB, acc, w, lane);
  int wm = (w >> 1) * 64, wn = (w & 1) * 64, lr = lane & 15, lk = lane >> 4;
#pragma unroll
  for (int mi = 0; mi < 4; ++mi)
#pragma unroll
    for (int ni = 0; ni < 4; ++ni)
#pragma unroll
      for (int r = 0; r < 4; ++r) {
        int m = m0 + wm + mi * 16 + lk * 4 + r;
        int n = n0 + wn + ni * 16 + lr;
        KtVTh[((size_t)b << 20) + ((size_t)n << 10) + m] = f2bh(acc[mi][ni][r]);
      }
}

// ---- G3 fused: y = Q @ KtV, then GroupNorm(32-ch groups) + transposed store out[b][d][t].
__global__ __launch_bounds__(256) void k_gemm3g(const u16* __restrict__ Qh, const u16* __restrict__ KtVTh,
                                                const float* __restrict__ gw, const float* __restrict__ gb,
                                                float* __restrict__ out) {
  __shared__ u16 sA[128 * 64], sB[128 * 64];
  fx4 acc[4][4];
#pragma unroll
  for (int i = 0; i < 4; ++i)
#pragma unroll
    for (int j = 0; j < 4; ++j) acc[i][j] = fx4{0.f, 0.f, 0.f, 0.f};
  int b = blockIdx.z;
  int m0 = blockIdx.x << 7, n0 = blockIdx.y << 7;
  int tid = threadIdx.x, lane = tid & 63, w = tid >> 6;
  gemm_core_hi64(Qh, (size_t)(b * 2048 + m0), 1024, KtVTh + ((size_t)b << 20), (size_t)n0, 1024, 1024,
                 sA, sB, acc, w, lane);
  int wm = (w >> 1) * 64, wn = (w & 1) * 64, lr = lane & 15, lk = lane >> 4;
  float wv[4], bvv[4];
#pragma unroll
  for (int ni = 0; ni < 4; ++ni) {
    int n = n0 + wn + ni * 16 + lr;
    wv[ni] = gw[n];
    bvv[ni] = gb[n];
  }
#pragma unroll
  for (int mi = 0; mi < 4; ++mi) {
    fx4 o0, o1, o2, o3;
#pragma unroll
    for (int r = 0; r < 4; ++r) {
      float v0 = acc[mi][0][r], v1 = acc[mi][1][r], v2 = acc[mi][2][r], v3 = acc[mi][3][r];
      float sA2 = v0 + v1, sB2 = v2 + v3;
#pragma unroll
      for (int mk = 1; mk <= 8; mk <<= 1) {
        sA2 += __shfl_xor(sA2, mk);
        sB2 += __shfl_xor(sB2, mk);
      }
      float mA = sA2 * (1.f / 32.f), mB = sB2 * (1.f / 32.f);
      float dA = (v0 - mA) * (v0 - mA) + (v1 - mA) * (v1 - mA);
      float dB = (v2 - mB) * (v2 - mB) + (v3 - mB) * (v3 - mB);
#pragma unroll
      for (int mk = 1; mk <= 8; mk <<= 1) {
        dA += __shfl_xor(dA, mk);
        dB += __shfl_xor(dB, mk);
      }
      float rA = rsqrtf(dA * (1.f / 32.f) + 1e-5f);
      float rB = rsqrtf(dB * (1.f / 32.f) + 1e-5f);
      o0[r] = (v0 - mA) * rA * wv[0] + bvv[0];
      o1[r] = (v1 - mA) * rA * wv[1] + bvv[1];
      o2[r] = (v2 - mB) * rB * wv[2] + bvv[2];
      o3[r] = (v3 - mB) * rB * wv[3] + bvv[3];
    }
    int mbase = m0 + wm + mi * 16 + lk * 4;  // t index, 16B-aligned
#pragma unroll
    for (int ni = 0; ni < 4; ++ni) {
      int n = n0 + wn + ni * 16 + lr;
      fx4 ov = (ni == 0) ? o0 : (ni == 1) ? o1 : (ni == 2) ? o2 : o3;
      *reinterpret_cast<fx4*>(out + (((size_t)(b << 10) + n) << 11) + mbase) = ov;
    }
  }
}

extern "C" void kernel_launch(void* const* d_in, const int* in_sizes, int n_in,
                              void* d_out, int out_size, void* d_ws, size_t ws_size,
                              hipStream_t stream) {
  const float* x = (const float*)d_in[0];
  const float* W = (const float*)d_in[1];
  const float* b_in = (const float*)d_in[2];
  const float* gnw = (const float*)d_in[3];
  const float* gnb = (const float*)d_in[4];
  float* out = (float*)d_out;
  char* ws = (char*)d_ws;

  // Workspace (bytes): xh@0(16M) WTh@16M(6M) Qh@22M(16M) Kth@38M(16M) Vth@54M(16M)
  // KtVTh@70M(8M) tabTI@78M(8M) tabIT@86M(8M). Total ~94MB.
  u16* xh = (u16*)(ws + 0);
  u16* WTh = (u16*)(ws + 16777216);
  u16* Qh = (u16*)(ws + 23068672);
  u16* Kth = (u16*)(ws + 39845888);
  u16* Vth = (u16*)(ws + 56623104);
  u16* KtVTh = (u16*)(ws + 73400320);
  float2* tabTI = (float2*)(ws + 81788928);
  float2* tabIT = (float2*)(ws + 90177536);

  k_ropetab<<<dim3(4096, 2), 256, 0, stream>>>(tabTI, tabIT);
  k_transW<<<dim3(96, 32), 256, 0, stream>>>(W, WTh);
  k_castX<<<4096, 256, 0, stream>>>(x, xh);
  k_gemm1f<<<1536, 256, 0, stream>>>(xh, WTh, b_in, tabTI, tabIT, Qh, Kth, Vth);
  k_gemm2<<<dim3(8, 8, 4), 256, 0, stream>>>(Kth, Vth, KtVTh);
  k_gemm3g<<<dim3(16, 8, 4), 256, 0, stream>>>(Qh, KtVTh, gnw, gnb, out);
}